// Round 3
// baseline (442.202 us; speedup 1.0000x reference)
//
#include <hip/hip_runtime.h>

#define EPS 1e-6f

typedef __attribute__((ext_vector_type(8))) __bf16 bf16x8;
typedef __attribute__((ext_vector_type(4))) float f32x4;
typedef __attribute__((ext_vector_type(4))) unsigned short us4v;
typedef __attribute__((ext_vector_type(8))) unsigned short us8v;
typedef unsigned short us;

__device__ inline us f2bf(float f) {
  unsigned int u = __builtin_bit_cast(unsigned int, f);
  unsigned int r = (u + 0x7fffu + ((u >> 16) & 1u)) >> 16;
  return (us)r;
}
__device__ inline float bf2f(us s) {
  unsigned int u = ((unsigned int)s) << 16;
  return __builtin_bit_cast(float, u);
}

__device__ inline void gl_lds16(const us* g, us* l) {
  __builtin_amdgcn_global_load_lds(
      (const __attribute__((address_space(1))) unsigned int*)g,
      (__attribute__((address_space(3))) unsigned int*)l, 16, 0, 0);
}

// ---------------------------------------------------------------------------
// fp32 -> bf16 convert (RNE), n elements (multiple of 2048). grid = n/2048.
// ---------------------------------------------------------------------------
__global__ __launch_bounds__(256) void conv_bf16(const float* __restrict__ s,
                                                 us* __restrict__ d) {
  int idx = blockIdx.x * 256 + threadIdx.x;
  size_t base = (size_t)idx * 8;
  float4 a = *(const float4*)(s + base);
  float4 b = *(const float4*)(s + base + 4);
  us8v o;
  o[0] = f2bf(a.x); o[1] = f2bf(a.y); o[2] = f2bf(a.z); o[3] = f2bf(a.w);
  o[4] = f2bf(b.x); o[5] = f2bf(b.y); o[6] = f2bf(b.z); o[7] = f2bf(b.w);
  *(us8v*)(d + base) = o;
}

// ---------------------------------------------------------------------------
// Projection GEMM — 8-phase counted-vmcnt template (T2+T3+T4+T5), plain HIP.
//   BM=BN=256, BK=64, 512 thr / 8 waves (2M x 4N), per-wave out 128x64.
//   LDS: As[2]/Bs[2] double-buffered K-tiles, 4 x 32 KB = 128 KiB.
//   XOR swizzle: granule(16B) ^= row&7 (write via pre-swizzled global src,
//   read via swizzled ds_read addr) -> conflict-free ds_read_b128.
//
// Window m (K-tile m, buf b=m&1), 4 phases, each = {ds_read ; stage 1
// half-tile ; s_barrier ; lgkmcnt(0)+sched_barrier ; setprio(1) ; 16 MFMA ;
// setprio(0) ; s_barrier}:
//   ph0: read B-all(8)+A-pair0(4); stage A0(m+1)   [A(m+1) buf freed by
//        tile m-1's end-barrier -> issue-after-consumption, provably safe]
//   ph1: A-pair1; stage A1(m+1)
//   ph2: A-pair2; stage B0(m+2)  [B(m) fully consumed in ph0; issue after
//        ph0 end-barrier -> safe]
//   ph3: A-pair3; stage B1(m+2); vmcnt(4); s_barrier
// vmcnt(4) ledger: 4 newest in-flight = B(m+2); guarantees A(m+1),B(m+1)
// landed = exactly tile m+1. Issue->use margin >= 2 phases (~1300cy) > HBM
// latency; a late landing stalls vmcnt (correct), an early landing cannot
// corrupt (all writes issued after the consuming phase's end-barrier).
// Tail: m=14 stages A(15) only then vmcnt(0); m=15 stages nothing.
//
// Y[i][j] = act( sum_k X[i][k] * W[j][k] + bias[j] )
// MODE 0: phi (elu+1), bf16 row-major      MODE 1: phi, bf16 per-head kt
// MODE 2: id, bf16 per-head vt             MODE 3: id, fp32 row-major
// grid 256 (1/CU), XCD-bijective swizzle: xcd=bid&7 owns 8 rowg x 4 colg
// -> W panels L2-resident per XCD, X row-panels reused by 4 blocks.
// ---------------------------------------------------------------------------
template <int MODE>
__global__ __launch_bounds__(512, 2) void proj_gemm(const us* __restrict__ X,
                                                    const us* __restrict__ W,
                                                    const float* __restrict__ bias,
                                                    void* __restrict__ Yv) {
  __shared__ alignas(16) us As[2][256 * 64];
  __shared__ alignas(16) us Bs[2][256 * 64];

  const int t = threadIdx.x;
  const int wave = t >> 6, lane = t & 63;
  const int q4 = lane >> 4, l16 = lane & 15;
  const int wm = wave >> 2, wn = wave & 3;   // 2(M) x 4(N) wave grid
  const int bid = blockIdx.x;
  const int rowg = (bid & 7) * 8 + (bid >> 5);  // 0..63
  const int colg = (bid >> 3) & 3;              // 0..3
  const int rowBase = rowg << 8;
  const int colBase = colg << 8;

  // staging source (pre-swizzled granule); dest is linear (HW adds lane*16B)
  const int tr = t >> 3;                       // row-within-64 = wave*8+(lane>>3)
  const int gsw = ((t & 7) ^ (tr & 7)) * 8;    // swizzled source granule (us)
  const us* Xg = X + (size_t)(rowBase + tr) * 1024 + gsw;
  const us* Wg = W + (size_t)(colBase + tr) * 1024 + gsw;

  // read-side swizzled granule offsets (us), per k-slice ks=0/1
  const int gx0 = ((0 | q4) ^ (l16 & 7)) * 8;
  const int gx1 = ((4 | q4) ^ (l16 & 7)) * 8;
  const int arow_off = (wm * 128 + l16) * 64;
  const int brow_off = (wn * 64 + l16) * 64;

  f32x4 acc[8][4];
#pragma unroll
  for (int i = 0; i < 8; i++)
#pragma unroll
    for (int j = 0; j < 4; j++) acc[i][j] = (f32x4){0.f, 0.f, 0.f, 0.f};

#define STAGE_A(kt, h)                                                      \
  {                                                                         \
    us* d_ = &As[(kt) & 1][((h) * 128 + wave * 8) * 64];                    \
    const us* s_ = Xg + (size_t)((h) * 128) * 1024 + (kt) * 64;             \
    gl_lds16(s_, d_);                                                       \
    gl_lds16(s_ + (size_t)64 * 1024, d_ + 64 * 64);                         \
  }
#define STAGE_B(kt, h)                                                      \
  {                                                                         \
    us* d_ = &Bs[(kt) & 1][((h) * 128 + wave * 8) * 64];                    \
    const us* s_ = Wg + (size_t)((h) * 128) * 1024 + (kt) * 64;             \
    gl_lds16(s_, d_);                                                       \
    gl_lds16(s_ + (size_t)64 * 1024, d_ + 64 * 64);                         \
  }
#define PH_SYNC_PRE()                                                       \
  asm volatile("s_barrier" ::: "memory");                                   \
  asm volatile("s_waitcnt lgkmcnt(0)" ::: "memory");                        \
  __builtin_amdgcn_sched_barrier(0);                                        \
  __builtin_amdgcn_s_setprio(1);
#define PH_SYNC_POST()                                                      \
  __builtin_amdgcn_s_setprio(0);                                           \
  asm volatile("s_barrier" ::: "memory");
#define MFMA16(J, AF)                                                       \
  _Pragma("unroll") for (int s_i = 0; s_i < 2; ++s_i)                       \
  _Pragma("unroll") for (int ks = 0; ks < 2; ++ks)                          \
  _Pragma("unroll") for (int ni = 0; ni < 4; ++ni)                          \
    acc[2 * (J) + s_i][ni] = __builtin_amdgcn_mfma_f32_16x16x32_bf16(       \
        AF[s_i][ks], bfv[ni][ks], acc[2 * (J) + s_i][ni], 0, 0, 0);

  // prologue: B(0), A(0), B(1); allow B(1) in flight
  STAGE_B(0, 0); STAGE_B(0, 1);
  STAGE_A(0, 0); STAGE_A(0, 1);
  STAGE_B(1, 0); STAGE_B(1, 1);
  asm volatile("s_waitcnt vmcnt(4)" ::: "memory");
  asm volatile("s_barrier" ::: "memory");

#pragma unroll 2
  for (int m = 0; m < 16; ++m) {
    const int b = m & 1;
    const us* Ar = &As[b][arow_off];
    const us* Br = &Bs[b][brow_off];
    bf16x8 bfv[4][2];

    // ---- phase 0: B-all + A-pair0 ; stage A0(m+1) ----
    {
      bf16x8 af[2][2];
#pragma unroll
      for (int s_i = 0; s_i < 2; ++s_i) {
        af[s_i][0] = *(const bf16x8*)(Ar + (0 + s_i) * 1024 + gx0);
        af[s_i][1] = *(const bf16x8*)(Ar + (0 + s_i) * 1024 + gx1);
      }
#pragma unroll
      for (int ni = 0; ni < 4; ++ni) {
        bfv[ni][0] = *(const bf16x8*)(Br + ni * 1024 + gx0);
        bfv[ni][1] = *(const bf16x8*)(Br + ni * 1024 + gx1);
      }
      if (m < 15) STAGE_A(m + 1, 0);
      PH_SYNC_PRE();
      MFMA16(0, af);
      PH_SYNC_POST();
    }
    // ---- phase 1: A-pair1 ; stage A1(m+1) ----
    {
      bf16x8 af[2][2];
#pragma unroll
      for (int s_i = 0; s_i < 2; ++s_i) {
        af[s_i][0] = *(const bf16x8*)(Ar + (2 + s_i) * 1024 + gx0);
        af[s_i][1] = *(const bf16x8*)(Ar + (2 + s_i) * 1024 + gx1);
      }
      if (m < 15) STAGE_A(m + 1, 1);
      PH_SYNC_PRE();
      MFMA16(1, af);
      PH_SYNC_POST();
    }
    // ---- phase 2: A-pair2 ; stage B0(m+2) ----
    {
      bf16x8 af[2][2];
#pragma unroll
      for (int s_i = 0; s_i < 2; ++s_i) {
        af[s_i][0] = *(const bf16x8*)(Ar + (4 + s_i) * 1024 + gx0);
        af[s_i][1] = *(const bf16x8*)(Ar + (4 + s_i) * 1024 + gx1);
      }
      if (m < 14) STAGE_B(m + 2, 0);
      PH_SYNC_PRE();
      MFMA16(2, af);
      PH_SYNC_POST();
    }
    // ---- phase 3: A-pair3 ; stage B1(m+2) ; vmcnt checkpoint ----
    {
      bf16x8 af[2][2];
#pragma unroll
      for (int s_i = 0; s_i < 2; ++s_i) {
        af[s_i][0] = *(const bf16x8*)(Ar + (6 + s_i) * 1024 + gx0);
        af[s_i][1] = *(const bf16x8*)(Ar + (6 + s_i) * 1024 + gx1);
      }
      if (m < 14) STAGE_B(m + 2, 1);
      asm volatile("s_barrier" ::: "memory");
      asm volatile("s_waitcnt lgkmcnt(0)" ::: "memory");
      __builtin_amdgcn_sched_barrier(0);
      __builtin_amdgcn_s_setprio(1);
      MFMA16(3, af);
      __builtin_amdgcn_s_setprio(0);
      if (m < 14)
        asm volatile("s_waitcnt vmcnt(4)" ::: "memory");
      else
        asm volatile("s_waitcnt vmcnt(0)" ::: "memory");
      asm volatile("s_barrier" ::: "memory");
    }
  }
#undef STAGE_A
#undef STAGE_B
#undef PH_SYNC_PRE
#undef PH_SYNC_POST
#undef MFMA16

  // epilogue
#pragma unroll
  for (int j = 0; j < 4; j++) {
    int col = colBase + wn * 64 + j * 16 + l16;
    float bv = bias[col];
#pragma unroll
    for (int i = 0; i < 8; i++) {
      int row0 = rowBase + wm * 128 + i * 16 + q4 * 4;
      if (MODE == 1 || MODE == 2) {
        int bb = row0 >> 12, m0 = row0 & 4095;
        int h = col >> 6, dd = col & 63;
        us4v pk;
#pragma unroll
        for (int r = 0; r < 4; r++) {
          float y = acc[i][j][r] + bv;
          if (MODE == 1) y = (y > 0.f) ? (y + 1.f) : __expf(y);
          pk[r] = f2bf(y);
        }
        *(us4v*)&((us*)Yv)[(((size_t)((bb * 16 + h) * 64 + dd)) << 12) + m0] = pk;
      } else {
#pragma unroll
        for (int r = 0; r < 4; r++) {
          float y = acc[i][j][r] + bv;
          if (MODE == 0) {
            y = (y > 0.f) ? (y + 1.f) : __expf(y);
            ((us*)Yv)[(size_t)(row0 + r) * 1024 + col] = f2bf(y);
          } else {
            ((float*)Yv)[(size_t)(row0 + r) * 1024 + col] = y;
          }
        }
      }
    }
  }
}

// ---------------------------------------------------------------------------
// kv stage 1: partial kv_t[e][d] = sum_m vt[e][m]*kt[d][m] over a 1024-m slab,
// plus z-partials folded from the kt B-fragments. 256 blocks (bh x 4 splits),
// 4 waves each covering 256 m. LDS tree-reduce, plain stores (no atomics).
// ---------------------------------------------------------------------------
__global__ __launch_bounds__(256) void kv_stage1(const us* __restrict__ kt,
                                                 const us* __restrict__ vt,
                                                 float* __restrict__ part,
                                                 float* __restrict__ zpart) {
  __shared__ float red[4][4096];
  __shared__ float zred[4][64][4];

  const int blk = blockIdx.x;
  const int bh = blk >> 2, split = blk & 3;
  const int t = threadIdx.x;
  const int w = t >> 6, lane = t & 63;
  const int q4 = lane >> 4, l16 = lane & 15;
  const us* ktb = kt + (size_t)bh * 64 * 4096;
  const us* vtb = vt + (size_t)bh * 64 * 4096;
  const int mbeg = split * 1024 + w * 256;

  f32x4 acc[4][4];
#pragma unroll
  for (int i = 0; i < 4; i++)
#pragma unroll
    for (int j = 0; j < 4; j++) acc[i][j] = (f32x4){0.f, 0.f, 0.f, 0.f};
  float zacc[4] = {0.f, 0.f, 0.f, 0.f};

  for (int m0 = mbeg; m0 < mbeg + 256; m0 += 32) {
    bf16x8 af[4], bfr[4];
#pragma unroll
    for (int i = 0; i < 4; i++)
      af[i] = *(const bf16x8*)&vtb[(size_t)(i * 16 + l16) * 4096 + m0 + q4 * 8];
#pragma unroll
    for (int j = 0; j < 4; j++) {
      us8v ub = *(const us8v*)&ktb[(size_t)(j * 16 + l16) * 4096 + m0 + q4 * 8];
      bfr[j] = __builtin_bit_cast(bf16x8, ub);
#pragma unroll
      for (int e = 0; e < 8; e++) zacc[j] += bf2f(ub[e]);
    }
#pragma unroll
    for (int i = 0; i < 4; i++)
#pragma unroll
      for (int j = 0; j < 4; j++)
        acc[i][j] = __builtin_amdgcn_mfma_f32_16x16x32_bf16(af[i], bfr[j], acc[i][j], 0, 0, 0);
  }

#pragma unroll
  for (int i = 0; i < 4; i++)
#pragma unroll
    for (int j = 0; j < 4; j++)
#pragma unroll
      for (int r = 0; r < 4; r++)
        red[w][(i * 16 + q4 * 4 + r) * 64 + j * 16 + l16] = acc[i][j][r];
#pragma unroll
  for (int j = 0; j < 4; j++) zred[w][j * 16 + l16][q4] = zacc[j];
  __syncthreads();

  float* pb = part + (size_t)blk * 4096;
#pragma unroll
  for (int i = 0; i < 16; i++) {
    int idx = t + 256 * i;
    pb[idx] = red[0][idx] + red[1][idx] + red[2][idx] + red[3][idx];
  }
  if (t < 64) {
    float s = 0.f;
#pragma unroll
    for (int w2 = 0; w2 < 4; w2++)
#pragma unroll
      for (int q = 0; q < 4; q++) s += zred[w2][t][q];
    zpart[blk * 64 + t] = s;
  }
}

// stage 2: reduce the 4 split-partials -> kv bf16 + z fp32. 64 blocks.
__global__ __launch_bounds__(256) void kv_stage2(const float* __restrict__ part,
                                                 const float* __restrict__ zpart,
                                                 us* __restrict__ kvb,
                                                 float* __restrict__ z) {
  const int bh = blockIdx.x;
  const int t = threadIdx.x;
  const float* p0 = part + (size_t)bh * 4 * 4096;
#pragma unroll
  for (int i = 0; i < 16; i++) {
    int idx = t + 256 * i;
    float s = p0[idx] + p0[4096 + idx] + p0[8192 + idx] + p0[12288 + idx];
    kvb[(size_t)bh * 4096 + idx] = f2bf(s);
  }
  if (t < 64) {
    const float* zp = zpart + (size_t)bh * 4 * 64;
    z[bh * 64 + t] = zp[t] + zp[64 + t] + zp[128 + t] + zp[192 + t];
  }
}

// ---------------------------------------------------------------------------
// attn[b][n][h*64+e] = (sum_d q[n][d] kv[d][e]) / (q[n]·z + eps), bf16,
// written IN PLACE over q (each block reads exactly the region it writes).
// ---------------------------------------------------------------------------
__global__ __launch_bounds__(256) void attn_kernel(const us* __restrict__ q,
                                                   const us* __restrict__ kvb,
                                                   const float* __restrict__ z,
                                                   us* __restrict__ attn) {
  __shared__ alignas(16) us kvs[64 * 72];
  __shared__ float zs[64];
  __shared__ float invden[256];

  const int bid = blockIdx.x;
  const int bh = bid >> 4, nc = bid & 15;
  const int b = bh >> 4, h = bh & 15;
  const int n0 = nc * 256;
  const int t = threadIdx.x;
  const int wave = t >> 6, lane = t & 63;
  const int q4 = lane >> 4, l16 = lane & 15;

#pragma unroll
  for (int i = 0; i < 2; i++) {
    int chunk = t + 256 * i;          // 0..511
    int e = chunk >> 3, d8 = chunk & 7;
    us8v vv = *(const us8v*)&kvb[(size_t)bh * 4096 + chunk * 8];
    *(us8v*)&kvs[e * 72 + d8 * 8] = vv;
  }
  if (t < 64) zs[t] = z[bh * 64 + t];
  __syncthreads();

  {
    const us* qrow = q + ((size_t)(b * 4096 + n0 + t)) * 1024 + h * 64;
    float s = 0.f;
#pragma unroll
    for (int d0 = 0; d0 < 64; d0 += 8) {
      us8v v = *(const us8v*)(qrow + d0);
#pragma unroll
      for (int j = 0; j < 8; j++) s += bf2f(v[j]) * zs[d0 + j];
    }
    invden[t] = 1.0f / (s + EPS);
  }
  __syncthreads();

  f32x4 acc[4][4];
#pragma unroll
  for (int i = 0; i < 4; i++)
#pragma unroll
    for (int j = 0; j < 4; j++) acc[i][j] = (f32x4){0.f, 0.f, 0.f, 0.f};

  const us* qb = q + ((size_t)(b * 4096 + n0 + wave * 64)) * 1024 + h * 64;
#pragma unroll
  for (int ks = 0; ks < 2; ks++) {
    bf16x8 af[4], bfr[4];
#pragma unroll
    for (int i = 0; i < 4; i++)
      af[i] = *(const bf16x8*)(qb + (size_t)(i * 16 + l16) * 1024 + ks * 32 + q4 * 8);
#pragma unroll
    for (int j = 0; j < 4; j++)
      bfr[j] = *(const bf16x8*)&kvs[(j * 16 + l16) * 72 + ks * 32 + q4 * 8];
#pragma unroll
    for (int i = 0; i < 4; i++)
#pragma unroll
      for (int j = 0; j < 4; j++)
        acc[i][j] = __builtin_amdgcn_mfma_f32_16x16x32_bf16(af[i], bfr[j], acc[i][j], 0, 0, 0);
  }

  us* ab = attn + ((size_t)(b * 4096 + n0 + wave * 64)) * 1024 + h * 64;
#pragma unroll
  for (int i = 0; i < 4; i++)
#pragma unroll
    for (int j = 0; j < 4; j++)
#pragma unroll
      for (int r = 0; r < 4; r++) {
        int rowl = i * 16 + q4 * 4 + r;
        int nl = wave * 64 + rowl;
        int e = j * 16 + l16;
        ab[(size_t)rowl * 1024 + e] = f2bf(acc[i][j][r] * invden[nl]);
      }
}

// ---------------------------------------------------------------------------
extern "C" void kernel_launch(void* const* d_in, const int* in_sizes, int n_in,
                              void* d_out, int out_size, void* d_ws, size_t ws_size,
                              hipStream_t stream) {
  const float* queries = (const float*)d_in[0];
  const float* keys    = (const float*)d_in[1];
  const float* values  = (const float*)d_in[2];
  const float* wq = (const float*)d_in[3];
  const float* bq = (const float*)d_in[4];
  const float* wk = (const float*)d_in[5];
  const float* bk = (const float*)d_in[6];
  const float* wv = (const float*)d_in[7];
  const float* bv = (const float*)d_in[8];
  const float* wo = (const float*)d_in[9];
  const float* bo = (const float*)d_in[10];

  char* ws = (char*)d_ws;
  const size_t TB = (size_t)16384 * 1024 * 2;   // 33.55 MB per big bf16 buffer
  us* A   = (us*)(ws);            // kt, later q/attn
  us* Bb  = (us*)(ws + TB);       // vt, later queries-bf16
  us* Xb  = (us*)(ws + 2 * TB);   // keys/values bf16 scratch
  us* wqb = (us*)(ws + 3 * TB);
  us* wkb = wqb + (size_t)1024 * 1024;
  us* wvb = wkb + (size_t)1024 * 1024;
  us* wob = wvb + (size_t)1024 * 1024;
  float* part  = (float*)(wob + (size_t)1024 * 1024);     // 256*4096 fp32
  float* zpart = part + (size_t)256 * 4096;               // 256*64
  float* z     = zpart + 256 * 64;                        // 4096
  us* kvb      = (us*)(z + 4096);                         // 64*4096 bf16

  const int GRID_IN = 16384 * 1024 / 2048;   // 8192
  const int GRID_W  = 1024 * 1024 / 2048;    // 512

  // weights -> bf16
  conv_bf16<<<GRID_W, 256, 0, stream>>>(wq, wqb);
  conv_bf16<<<GRID_W, 256, 0, stream>>>(wk, wkb);
  conv_bf16<<<GRID_W, 256, 0, stream>>>(wv, wvb);
  conv_bf16<<<GRID_W, 256, 0, stream>>>(wo, wob);

  // K projection
  conv_bf16<<<GRID_IN, 256, 0, stream>>>(keys, Xb);
  proj_gemm<1><<<256, 512, 0, stream>>>(Xb, wkb, bk, (void*)A);
  // V projection
  conv_bf16<<<GRID_IN, 256, 0, stream>>>(values, Xb);
  proj_gemm<2><<<256, 512, 0, stream>>>(Xb, wvb, bv, (void*)Bb);
  // kv + z
  kv_stage1<<<256, 256, 0, stream>>>(A, Bb, part, zpart);
  kv_stage2<<<64, 256, 0, stream>>>(part, zpart, kvb, z);
  // Q projection (kt/vt dead; reuse buffers)
  conv_bf16<<<GRID_IN, 256, 0, stream>>>(queries, Bb);
  proj_gemm<0><<<256, 512, 0, stream>>>(Bb, wqb, bq, (void*)A);
  // attention (in place over q)
  attn_kernel<<<1024, 256, 0, stream>>>(A, kvb, z, A);
  // output projection
  proj_gemm<3><<<256, 512, 0, stream>>>(A, wob, bo, d_out);
}

// Round 4
// 436.261 us; speedup vs baseline: 1.0136x; 1.0136x over previous
//
#include <hip/hip_runtime.h>

#define EPS 1e-6f

typedef __attribute__((ext_vector_type(8))) __bf16 bf16x8;
typedef __attribute__((ext_vector_type(4))) float f32x4;
typedef __attribute__((ext_vector_type(4))) unsigned short us4v;
typedef __attribute__((ext_vector_type(8))) unsigned short us8v;
typedef unsigned short us;

__device__ inline us f2bf(float f) {
  unsigned int u = __builtin_bit_cast(unsigned int, f);
  unsigned int r = (u + 0x7fffu + ((u >> 16) & 1u)) >> 16;
  return (us)r;
}
__device__ inline float bf2f(us s) {
  unsigned int u = ((unsigned int)s) << 16;
  return __builtin_bit_cast(float, u);
}
// packed fp32->bf16 (RNE), lo=cvt(a), hi=cvt(b). No builtin on gfx950.
__device__ inline unsigned int cvtpk(float a, float b) {
  unsigned int d;
  asm("v_cvt_pk_bf16_f32 %0, %1, %2" : "=v"(d) : "v"(a), "v"(b));
  return d;
}

__device__ inline void gl_lds16(const us* g, us* l) {
  __builtin_amdgcn_global_load_lds(
      (const __attribute__((address_space(1))) unsigned int*)g,
      (__attribute__((address_space(3))) unsigned int*)l, 16, 0, 0);
}

// ---------------------------------------------------------------------------
// weights fp32 -> bf16 (all four in one launch). grid 2048: bid>>9 = matrix.
// ---------------------------------------------------------------------------
__global__ __launch_bounds__(256) void conv_w4(const float* __restrict__ wq,
                                               const float* __restrict__ wk,
                                               const float* __restrict__ wv,
                                               const float* __restrict__ wo,
                                               us* __restrict__ dq,
                                               us* __restrict__ dk,
                                               us* __restrict__ dv,
                                               us* __restrict__ dwo) {
  int bid = blockIdx.x;
  int msel = bid >> 9, lb = bid & 511;
  const float* s = (msel == 0) ? wq : (msel == 1) ? wk : (msel == 2) ? wv : wo;
  us* d = (msel == 0) ? dq : (msel == 1) ? dk : (msel == 2) ? dv : dwo;
  int idx = lb * 256 + threadIdx.x;
  size_t base = (size_t)idx * 8;
  float4 a = *(const float4*)(s + base);
  float4 b = *(const float4*)(s + base + 4);
  us8v o;
  o[0] = f2bf(a.x); o[1] = f2bf(a.y); o[2] = f2bf(a.z); o[3] = f2bf(a.w);
  o[4] = f2bf(b.x); o[5] = f2bf(b.y); o[6] = f2bf(b.z); o[7] = f2bf(b.w);
  *(us8v*)(d + base) = o;
}

// ---------------------------------------------------------------------------
// Projection GEMM, 8-phase schedule, with FUSED fp32->bf16 input conversion.
//   BM=BN=256, BK=64, 512 thr / 8 waves (2M x 4N), per-wave out 128x64.
//   LDS: As[2]/Bs[2] double-buffered K-tiles (bf16), 4 x 32 KB = 128 KiB.
//   B (weights, bf16): global_load_lds staging (unchanged, proven).
//   A (activations): REG-staged — global fp32 (MODE 0/1/2) or bf16 (MODE 3)
//     -> v_cvt_pk_bf16_f32 -> ds_write_b128 into the IDENTICAL linear+XOR
//     LDS layout the gl_lds path used. Read side / MFMA / epilogue unchanged.
//
// Per-window (K-tile m) ledger, issue order [A0,A1 loads | B0,B1 gl_lds]:
//   ph0: ds_read B-all+A-pair0; issue A0(m+1) loads (4 fp32 / 2 bf16)
//   ph1: ds_read A-pair1;       issue A1(m+1) loads
//   ph2: ds_read A-pair2; vmcnt(4|2) [A0 landed; forces older B(m+1) too];
//        cvt+ds_write A-half0; gl_lds B0(m+2)^2
//   ph3: ds_read A-pair3; vmcnt(2) [A1 landed]; cvt+write A-half1;
//        gl_lds B1(m+2)^2
// Each phase: ...; s_barrier; lgkmcnt(0); sched_barrier; setprio(1);
//             16 MFMA; setprio(0); s_barrier.
// Publish proof: ds_writes of ph2/ph3 are lgkm-completed by the SAME phase's
// post-barrier lgkmcnt(0), which precedes the window-end barrier -> all
// waves' A(m+1) writes visible before any wave reads tile m+1. A-writes go
// to As[(m+1)&1], reads come from As[m&1] — disjoint. B(m+2) lands in
// Bs[m&1] only after ph0's B-reads are in regs (2 barriers earlier). Safe.
// Tail: m=14 ph3 uses vmcnt(0); m=15 stages nothing.
//
// MODE 0: phi (elu+1), bf16 row-major      MODE 1: phi, bf16 per-head kt
// MODE 2: id, bf16 per-head vt             MODE 3: id, fp32 row-major (X bf16)
// grid 256 (1/CU), XCD-bijective swizzle: xcd=bid&7 owns 8 rowg x 4 colg.
// ---------------------------------------------------------------------------
template <int MODE>
__global__ __launch_bounds__(512, 2) void proj_gemm(const void* __restrict__ Xv,
                                                    const us* __restrict__ W,
                                                    const float* __restrict__ bias,
                                                    void* __restrict__ Yv) {
  constexpr bool FP32X = (MODE != 3);
  __shared__ alignas(16) us As[2][256 * 64];
  __shared__ alignas(16) us Bs[2][256 * 64];

  const float* Xf = (const float*)Xv;
  const us* Xh = (const us*)Xv;

  const int t = threadIdx.x;
  const int wave = t >> 6, lane = t & 63;
  const int q4 = lane >> 4, l16 = lane & 15;
  const int wm = wave >> 2, wn = wave & 3;   // 2(M) x 4(N) wave grid
  const int bid = blockIdx.x;
  const int rowg = (bid & 7) * 8 + (bid >> 5);  // 0..63
  const int colg = (bid >> 3) & 3;              // 0..3
  const int rowBase = rowg << 8;
  const int colBase = colg << 8;

  // staging geometry (identical to gl_lds layout): thread t covers
  // row (h*128 + r*64 + tr), k-granule g8 = ((t&7)^(tr&7))*8 elems.
  const int tr = t >> 3;
  const int g8 = ((t & 7) ^ (tr & 7)) * 8;
  const us* Wg = W + (size_t)(colBase + tr) * 1024 + g8;

  // read-side swizzled granule offsets (us), per k-slice ks=0/1
  const int gx0 = ((0 | q4) ^ (l16 & 7)) * 8;
  const int gx1 = ((4 | q4) ^ (l16 & 7)) * 8;
  const int arow_off = (wm * 128 + l16) * 64;
  const int brow_off = (wn * 64 + l16) * 64;

  float4 av[2][2][2];   // [half][round][8-float slot]  (FP32X path)
  uint4 aw[2][2];       // [half][round]                (bf16  path)

  f32x4 acc[8][4];
#pragma unroll
  for (int i = 0; i < 8; i++)
#pragma unroll
    for (int j = 0; j < 4; j++) acc[i][j] = (f32x4){0.f, 0.f, 0.f, 0.f};

#define ISSUE_A(kt, h)                                                       \
  if constexpr (FP32X) {                                                     \
    const float* p_ = Xf + (size_t)(rowBase + (h) * 128 + tr) * 1024 +       \
                      (kt) * 64 + g8;                                        \
    av[h][0][0] = *(const float4*)p_;                                        \
    av[h][0][1] = *(const float4*)(p_ + 4);                                  \
    av[h][1][0] = *(const float4*)(p_ + 65536);                              \
    av[h][1][1] = *(const float4*)(p_ + 65536 + 4);                          \
  } else {                                                                   \
    const us* p_ = Xh + (size_t)(rowBase + (h) * 128 + tr) * 1024 +          \
                   (kt) * 64 + g8;                                           \
    aw[h][0] = *(const uint4*)p_;                                            \
    aw[h][1] = *(const uint4*)(p_ + 65536);                                  \
  }

#define WRITE_A(kt, h)                                                       \
  _Pragma("unroll") for (int r_ = 0; r_ < 2; ++r_) {                         \
    uint4 o_;                                                                \
    if constexpr (FP32X) {                                                   \
      o_.x = cvtpk(av[h][r_][0].x, av[h][r_][0].y);                          \
      o_.y = cvtpk(av[h][r_][0].z, av[h][r_][0].w);                          \
      o_.z = cvtpk(av[h][r_][1].x, av[h][r_][1].y);                          \
      o_.w = cvtpk(av[h][r_][1].z, av[h][r_][1].w);                          \
    } else {                                                                 \
      o_ = aw[h][r_];                                                        \
    }                                                                        \
    *(uint4*)&As[(kt) & 1][((h) * 128 + wave * 8) * 64 + r_ * 4096 +         \
                           lane * 8] = o_;                                   \
  }

#define STAGE_B(kt, h)                                                       \
  {                                                                          \
    us* d_ = &Bs[(kt) & 1][((h) * 128 + wave * 8) * 64];                     \
    const us* s_ = Wg + (size_t)((h) * 128) * 1024 + (kt) * 64;              \
    gl_lds16(s_, d_);                                                        \
    gl_lds16(s_ + (size_t)64 * 1024, d_ + 64 * 64);                          \
  }
#define PH_SYNC_PRE()                                                        \
  asm volatile("s_barrier" ::: "memory");                                    \
  asm volatile("s_waitcnt lgkmcnt(0)" ::: "memory");                         \
  __builtin_amdgcn_sched_barrier(0);                                         \
  __builtin_amdgcn_s_setprio(1);
#define PH_SYNC_POST()                                                       \
  __builtin_amdgcn_s_setprio(0);                                            \
  asm volatile("s_barrier" ::: "memory");
#define MFMA16(J, AF)                                                        \
  _Pragma("unroll") for (int s_i = 0; s_i < 2; ++s_i)                        \
  _Pragma("unroll") for (int ks = 0; ks < 2; ++ks)                           \
  _Pragma("unroll") for (int ni = 0; ni < 4; ++ni)                           \
    acc[2 * (J) + s_i][ni] = __builtin_amdgcn_mfma_f32_16x16x32_bf16(        \
        AF[s_i][ks], bfv[ni][ks], acc[2 * (J) + s_i][ni], 0, 0, 0);

  // prologue: B(0) gl_lds, A(0) reg-loads, B(1) gl_lds; wait leaves B(1).
  STAGE_B(0, 0); STAGE_B(0, 1);
  ISSUE_A(0, 0); ISSUE_A(0, 1);
  STAGE_B(1, 0); STAGE_B(1, 1);
  asm volatile("s_waitcnt vmcnt(4)" ::: "memory");
  WRITE_A(0, 0); WRITE_A(0, 1);
  asm volatile("s_waitcnt lgkmcnt(0)" ::: "memory");
  asm volatile("s_barrier" ::: "memory");

#pragma unroll 2
  for (int m = 0; m < 16; ++m) {
    const int b = m & 1;
    const us* Ar = &As[b][arow_off];
    const us* Br = &Bs[b][brow_off];
    bf16x8 bfv[4][2];

    // ---- phase 0: B-all + A-pair0 ; issue A0(m+1) loads ----
    {
      bf16x8 af[2][2];
#pragma unroll
      for (int s_i = 0; s_i < 2; ++s_i) {
        af[s_i][0] = *(const bf16x8*)(Ar + (0 + s_i) * 1024 + gx0);
        af[s_i][1] = *(const bf16x8*)(Ar + (0 + s_i) * 1024 + gx1);
      }
#pragma unroll
      for (int ni = 0; ni < 4; ++ni) {
        bfv[ni][0] = *(const bf16x8*)(Br + ni * 1024 + gx0);
        bfv[ni][1] = *(const bf16x8*)(Br + ni * 1024 + gx1);
      }
      if (m < 15) { ISSUE_A(m + 1, 0); }
      PH_SYNC_PRE();
      MFMA16(0, af);
      PH_SYNC_POST();
    }
    // ---- phase 1: A-pair1 ; issue A1(m+1) loads ----
    {
      bf16x8 af[2][2];
#pragma unroll
      for (int s_i = 0; s_i < 2; ++s_i) {
        af[s_i][0] = *(const bf16x8*)(Ar + (2 + s_i) * 1024 + gx0);
        af[s_i][1] = *(const bf16x8*)(Ar + (2 + s_i) * 1024 + gx1);
      }
      if (m < 15) { ISSUE_A(m + 1, 1); }
      PH_SYNC_PRE();
      MFMA16(1, af);
      PH_SYNC_POST();
    }
    // ---- phase 2: A-pair2 ; wait A0 -> cvt+write half0 ; gl_lds B0(m+2) ----
    {
      bf16x8 af[2][2];
#pragma unroll
      for (int s_i = 0; s_i < 2; ++s_i) {
        af[s_i][0] = *(const bf16x8*)(Ar + (4 + s_i) * 1024 + gx0);
        af[s_i][1] = *(const bf16x8*)(Ar + (4 + s_i) * 1024 + gx1);
      }
      if (m < 15) {
        if constexpr (FP32X)
          asm volatile("s_waitcnt vmcnt(4)" ::: "memory");
        else
          asm volatile("s_waitcnt vmcnt(2)" ::: "memory");
        WRITE_A(m + 1, 0);
      }
      if (m < 14) STAGE_B(m + 2, 0);
      PH_SYNC_PRE();
      MFMA16(2, af);
      PH_SYNC_POST();
    }
    // ---- phase 3: A-pair3 ; wait A1 -> cvt+write half1 ; gl_lds B1(m+2) ----
    {
      bf16x8 af[2][2];
#pragma unroll
      for (int s_i = 0; s_i < 2; ++s_i) {
        af[s_i][0] = *(const bf16x8*)(Ar + (6 + s_i) * 1024 + gx0);
        af[s_i][1] = *(const bf16x8*)(Ar + (6 + s_i) * 1024 + gx1);
      }
      if (m < 15) {
        if (m < 14)
          asm volatile("s_waitcnt vmcnt(2)" ::: "memory");
        else
          asm volatile("s_waitcnt vmcnt(0)" ::: "memory");
        WRITE_A(m + 1, 1);
      }
      if (m < 14) STAGE_B(m + 2, 1);
      PH_SYNC_PRE();
      MFMA16(3, af);
      PH_SYNC_POST();
    }
  }
#undef ISSUE_A
#undef WRITE_A
#undef STAGE_B
#undef PH_SYNC_PRE
#undef PH_SYNC_POST
#undef MFMA16

  // epilogue
#pragma unroll
  for (int j = 0; j < 4; j++) {
    int col = colBase + wn * 64 + j * 16 + l16;
    float bv = bias[col];
#pragma unroll
    for (int i = 0; i < 8; i++) {
      int row0 = rowBase + wm * 128 + i * 16 + q4 * 4;
      if (MODE == 1 || MODE == 2) {
        int bb = row0 >> 12, m0 = row0 & 4095;
        int h = col >> 6, dd = col & 63;
        us4v pk;
#pragma unroll
        for (int r = 0; r < 4; r++) {
          float y = acc[i][j][r] + bv;
          if (MODE == 1) y = (y > 0.f) ? (y + 1.f) : __expf(y);
          pk[r] = f2bf(y);
        }
        *(us4v*)&((us*)Yv)[(((size_t)((bb * 16 + h) * 64 + dd)) << 12) + m0] = pk;
      } else {
#pragma unroll
        for (int r = 0; r < 4; r++) {
          float y = acc[i][j][r] + bv;
          if (MODE == 0) {
            y = (y > 0.f) ? (y + 1.f) : __expf(y);
            ((us*)Yv)[(size_t)(row0 + r) * 1024 + col] = f2bf(y);
          } else {
            ((float*)Yv)[(size_t)(row0 + r) * 1024 + col] = y;
          }
        }
      }
    }
  }
}

// ---------------------------------------------------------------------------
// kv stage 1: partial kv_t[e][d] = sum_m vt[e][m]*kt[d][m] over a 1024-m slab,
// plus z-partials folded from the kt B-fragments. 256 blocks (bh x 4 splits),
// 4 waves each covering 256 m. LDS tree-reduce, plain stores (no atomics).
// ---------------------------------------------------------------------------
__global__ __launch_bounds__(256) void kv_stage1(const us* __restrict__ kt,
                                                 const us* __restrict__ vt,
                                                 float* __restrict__ part,
                                                 float* __restrict__ zpart) {
  __shared__ float red[4][4096];
  __shared__ float zred[4][64][4];

  const int blk = blockIdx.x;
  const int bh = blk >> 2, split = blk & 3;
  const int t = threadIdx.x;
  const int w = t >> 6, lane = t & 63;
  const int q4 = lane >> 4, l16 = lane & 15;
  const us* ktb = kt + (size_t)bh * 64 * 4096;
  const us* vtb = vt + (size_t)bh * 64 * 4096;
  const int mbeg = split * 1024 + w * 256;

  f32x4 acc[4][4];
#pragma unroll
  for (int i = 0; i < 4; i++)
#pragma unroll
    for (int j = 0; j < 4; j++) acc[i][j] = (f32x4){0.f, 0.f, 0.f, 0.f};
  float zacc[4] = {0.f, 0.f, 0.f, 0.f};

  for (int m0 = mbeg; m0 < mbeg + 256; m0 += 32) {
    bf16x8 af[4], bfr[4];
#pragma unroll
    for (int i = 0; i < 4; i++)
      af[i] = *(const bf16x8*)&vtb[(size_t)(i * 16 + l16) * 4096 + m0 + q4 * 8];
#pragma unroll
    for (int j = 0; j < 4; j++) {
      us8v ub = *(const us8v*)&ktb[(size_t)(j * 16 + l16) * 4096 + m0 + q4 * 8];
      bfr[j] = __builtin_bit_cast(bf16x8, ub);
#pragma unroll
      for (int e = 0; e < 8; e++) zacc[j] += bf2f(ub[e]);
    }
#pragma unroll
    for (int i = 0; i < 4; i++)
#pragma unroll
      for (int j = 0; j < 4; j++)
        acc[i][j] = __builtin_amdgcn_mfma_f32_16x16x32_bf16(af[i], bfr[j], acc[i][j], 0, 0, 0);
  }

#pragma unroll
  for (int i = 0; i < 4; i++)
#pragma unroll
    for (int j = 0; j < 4; j++)
#pragma unroll
      for (int r = 0; r < 4; r++)
        red[w][(i * 16 + q4 * 4 + r) * 64 + j * 16 + l16] = acc[i][j][r];
#pragma unroll
  for (int j = 0; j < 4; j++) zred[w][j * 16 + l16][q4] = zacc[j];
  __syncthreads();

  float* pb = part + (size_t)blk * 4096;
#pragma unroll
  for (int i = 0; i < 16; i++) {
    int idx = t + 256 * i;
    pb[idx] = red[0][idx] + red[1][idx] + red[2][idx] + red[3][idx];
  }
  if (t < 64) {
    float s = 0.f;
#pragma unroll
    for (int w2 = 0; w2 < 4; w2++)
#pragma unroll
      for (int q = 0; q < 4; q++) s += zred[w2][t][q];
    zpart[blk * 64 + t] = s;
  }
}

// stage 2: reduce the 4 split-partials -> kv bf16 + z fp32. 64 blocks.
__global__ __launch_bounds__(256) void kv_stage2(const float* __restrict__ part,
                                                 const float* __restrict__ zpart,
                                                 us* __restrict__ kvb,
                                                 float* __restrict__ z) {
  const int bh = blockIdx.x;
  const int t = threadIdx.x;
  const float* p0 = part + (size_t)bh * 4 * 4096;
#pragma unroll
  for (int i = 0; i < 16; i++) {
    int idx = t + 256 * i;
    float s = p0[idx] + p0[4096 + idx] + p0[8192 + idx] + p0[12288 + idx];
    kvb[(size_t)bh * 4096 + idx] = f2bf(s);
  }
  if (t < 64) {
    const float* zp = zpart + (size_t)bh * 4 * 64;
    z[bh * 64 + t] = zp[t] + zp[64 + t] + zp[128 + t] + zp[192 + t];
  }
}

// ---------------------------------------------------------------------------
// attn[b][n][h*64+e] = (sum_d q[n][d] kv[d][e]) / (q[n]·z + eps), bf16,
// written IN PLACE over q (each block reads exactly the region it writes).
// ---------------------------------------------------------------------------
__global__ __launch_bounds__(256) void attn_kernel(const us* __restrict__ q,
                                                   const us* __restrict__ kvb,
                                                   const float* __restrict__ z,
                                                   us* __restrict__ attn) {
  __shared__ alignas(16) us kvs[64 * 72];
  __shared__ float zs[64];
  __shared__ float invden[256];

  const int bid = blockIdx.x;
  const int bh = bid >> 4, nc = bid & 15;
  const int b = bh >> 4, h = bh & 15;
  const int n0 = nc * 256;
  const int t = threadIdx.x;
  const int wave = t >> 6, lane = t & 63;
  const int q4 = lane >> 4, l16 = lane & 15;

#pragma unroll
  for (int i = 0; i < 2; i++) {
    int chunk = t + 256 * i;          // 0..511
    int e = chunk >> 3, d8 = chunk & 7;
    us8v vv = *(const us8v*)&kvb[(size_t)bh * 4096 + chunk * 8];
    *(us8v*)&kvs[e * 72 + d8 * 8] = vv;
  }
  if (t < 64) zs[t] = z[bh * 64 + t];
  __syncthreads();

  {
    const us* qrow = q + ((size_t)(b * 4096 + n0 + t)) * 1024 + h * 64;
    float s = 0.f;
#pragma unroll
    for (int d0 = 0; d0 < 64; d0 += 8) {
      us8v v = *(const us8v*)(qrow + d0);
#pragma unroll
      for (int j = 0; j < 8; j++) s += bf2f(v[j]) * zs[d0 + j];
    }
    invden[t] = 1.0f / (s + EPS);
  }
  __syncthreads();

  f32x4 acc[4][4];
#pragma unroll
  for (int i = 0; i < 4; i++)
#pragma unroll
    for (int j = 0; j < 4; j++) acc[i][j] = (f32x4){0.f, 0.f, 0.f, 0.f};

  const us* qb = q + ((size_t)(b * 4096 + n0 + wave * 64)) * 1024 + h * 64;
#pragma unroll
  for (int ks = 0; ks < 2; ks++) {
    bf16x8 af[4], bfr[4];
#pragma unroll
    for (int i = 0; i < 4; i++)
      af[i] = *(const bf16x8*)(qb + (size_t)(i * 16 + l16) * 1024 + ks * 32 + q4 * 8);
#pragma unroll
    for (int j = 0; j < 4; j++)
      bfr[j] = *(const bf16x8*)&kvs[(j * 16 + l16) * 72 + ks * 32 + q4 * 8];
#pragma unroll
    for (int i = 0; i < 4; i++)
#pragma unroll
      for (int j = 0; j < 4; j++)
        acc[i][j] = __builtin_amdgcn_mfma_f32_16x16x32_bf16(af[i], bfr[j], acc[i][j], 0, 0, 0);
  }

  us* ab = attn + ((size_t)(b * 4096 + n0 + wave * 64)) * 1024 + h * 64;
#pragma unroll
  for (int i = 0; i < 4; i++)
#pragma unroll
    for (int j = 0; j < 4; j++)
#pragma unroll
      for (int r = 0; r < 4; r++) {
        int rowl = i * 16 + q4 * 4 + r;
        int nl = wave * 64 + rowl;
        int e = j * 16 + l16;
        ab[(size_t)rowl * 1024 + e] = f2bf(acc[i][j][r] * invden[nl]);
      }
}

// ---------------------------------------------------------------------------
extern "C" void kernel_launch(void* const* d_in, const int* in_sizes, int n_in,
                              void* d_out, int out_size, void* d_ws, size_t ws_size,
                              hipStream_t stream) {
  const float* queries = (const float*)d_in[0];
  const float* keys    = (const float*)d_in[1];
  const float* values  = (const float*)d_in[2];
  const float* wq = (const float*)d_in[3];
  const float* bq = (const float*)d_in[4];
  const float* wk = (const float*)d_in[5];
  const float* bk = (const float*)d_in[6];
  const float* wv = (const float*)d_in[7];
  const float* bv = (const float*)d_in[8];
  const float* wo = (const float*)d_in[9];
  const float* bo = (const float*)d_in[10];

  char* ws = (char*)d_ws;
  const size_t TB = (size_t)16384 * 1024 * 2;   // 33.55 MB per big bf16 buffer
  us* A   = (us*)(ws);            // kt, later q/attn
  us* Bb  = (us*)(ws + TB);       // vt
  us* wqb = (us*)(ws + 3 * TB);   // (2*TB gap kept for layout stability)
  us* wkb = wqb + (size_t)1024 * 1024;
  us* wvb = wkb + (size_t)1024 * 1024;
  us* wob = wvb + (size_t)1024 * 1024;
  float* part  = (float*)(wob + (size_t)1024 * 1024);     // 256*4096 fp32
  float* zpart = part + (size_t)256 * 4096;               // 256*64
  float* z     = zpart + 256 * 64;                        // 4096
  us* kvb      = (us*)(z + 4096);                         // 64*4096 bf16

  // weights -> bf16 (single launch)
  conv_w4<<<2048, 256, 0, stream>>>(wq, wk, wv, wo, wqb, wkb, wvb, wob);

  // K projection (fused fp32 read)
  proj_gemm<1><<<256, 512, 0, stream>>>((const void*)keys, wkb, bk, (void*)A);
  // V projection
  proj_gemm<2><<<256, 512, 0, stream>>>((const void*)values, wvb, bv, (void*)Bb);
  // kv + z
  kv_stage1<<<256, 256, 0, stream>>>(A, Bb, part, zpart);
  kv_stage2<<<64, 256, 0, stream>>>(part, zpart, kvb, z);
  // Q projection (kt dead; write q bf16 into A)
  proj_gemm<0><<<256, 512, 0, stream>>>((const void*)queries, wqb, bq, (void*)A);
  // attention (in place over q)
  attn_kernel<<<1024, 256, 0, stream>>>(A, kvb, z, A);
  // output projection (X = attn bf16)
  proj_gemm<3><<<256, 512, 0, stream>>>((const void*)A, wob, bo, d_out);
}